// Round 3
// baseline (705.635 us; speedup 1.0000x reference)
//
#include <hip/hip_runtime.h>
#include <hip/hip_cooperative_groups.h>

namespace cg = cooperative_groups;

// DynamicQuantizer fused single cooperative kernel.
// X: [8192, 4096] f32. Output f32 same shape.
//
//   Stage A: part = per-block X^T (X v0); fused frob, max|X|, max|X_adapt|; c -> LDS
//   Stage B: reduce part -> w1; merge stats into scal
//   Stage C: part = per-block X^T (X w1/||w1||)   (norm computed in-block)
//   Stage D: reduce part -> w2
//   Stage E: sigma^2 = ||X w2/||w2||||^2
//   Stage F: scale/flag derived per-block from scal; fake-quant grid-stride
//
// ws (floats): [0,4096) w1 | [4096,8192) w2 | [8192,8208) scal
//   scal: 8 sigma_sq, 9 frob, 10 max|X| bits, 11 max|X_adapt| bits
// d_out doubles as the 512x4096 partial buffer until stage F overwrites it.

#define NR 8192
#define HC 4096
#define H4 (HC / 4)
#define EPSV 1e-8f
#define NB 512
#define TPB 256
#define STRIDE (NB * TPB)

__device__ __forceinline__ float wave_sum(float v) {
#pragma unroll
    for (int m = 32; m; m >>= 1) v += __shfl_xor(v, m);
    return v;
}

__device__ __forceinline__ void flush_part(const float4 (&wa)[16], float4* wredA,
                                           float4* wredB, float4* dst, int t, int lane,
                                           int wid) {
    if (wid == 0) {
#pragma unroll
        for (int j = 0; j < 16; ++j) wredA[j * 64 + lane] = wa[j];
    } else if (wid == 1) {
#pragma unroll
        for (int j = 0; j < 16; ++j) wredB[j * 64 + lane] = wa[j];
    }
    __syncthreads();
    if (wid == 2) {
#pragma unroll
        for (int j = 0; j < 16; ++j) {
            float4 a = wredA[j * 64 + lane];
            a.x += wa[j].x; a.y += wa[j].y; a.z += wa[j].z; a.w += wa[j].w;
            wredA[j * 64 + lane] = a;
        }
    } else if (wid == 3) {
#pragma unroll
        for (int j = 0; j < 16; ++j) {
            float4 b = wredB[j * 64 + lane];
            b.x += wa[j].x; b.y += wa[j].y; b.z += wa[j].z; b.w += wa[j].w;
            wredB[j * 64 + lane] = b;
        }
    }
    __syncthreads();
#pragma unroll
    for (int k = 0; k < 4; ++k) {
        float4 a = wredA[t + k * TPB];
        float4 b = wredB[t + k * TPB];
        a.x += b.x; a.y += b.y; a.z += b.z; a.w += b.w;
        dst[t + k * TPB] = a;
    }
}

__global__ __launch_bounds__(TPB, 2) void mega_kernel(
    const float4* __restrict__ X4, const float* __restrict__ la,
    const float* __restrict__ lb, const float4* __restrict__ v04,
    float* __restrict__ w1, float* __restrict__ w2, float* __restrict__ scal,
    float4* __restrict__ part4, float4* __restrict__ out4) {
    __shared__ float4 csh[H4];    // 16 KB c = la*lb (resident through quant)
    __shared__ float4 vsh[H4];    // 16 KB staged vector
    __shared__ float4 wredA[H4];  // 16 KB cross-wave reduce
    __shared__ float4 wredB[H4];  // 16 KB
    __shared__ float smn[16];
    cg::grid_group grid = cg::this_grid();

    const int t = threadIdx.x;
    const int lane = t & 63;
    const int wid = t >> 6;
    const int bid = blockIdx.x;
    const int r0 = bid * 16 + wid * 4;
    const int gtid = bid * TPB + t;

    // ---------------- Stage A: X^T (X v0) + stats ----------------
    if (bid == 0) {
        if (t < 16) scal[t] = 0.f;
        for (int k = t; k < HC; k += TPB) { w1[k] = 0.f; w2[k] = 0.f; }
    }
#pragma unroll
    for (int k = 0; k < 4; ++k) {
        int idx = t + k * TPB;
        float4 A = reinterpret_cast<const float4*>(la)[idx];
        float4 B = reinterpret_cast<const float4*>(lb)[idx];
        csh[idx] = make_float4(A.x * B.x, A.y * B.y, A.z * B.z, A.w * B.w);
        vsh[idx] = v04[idx];
    }
    __syncthreads();

    float frob = 0.f, mx = 0.f, ma = 0.f;
    {
        float4 wa[16];
#pragma unroll
        for (int j = 0; j < 16; ++j) wa[j] = make_float4(0.f, 0.f, 0.f, 0.f);
        float4 cur[16];
#pragma unroll
        for (int i = 0; i < 4; ++i) {
            const float4* Xr = X4 + (size_t)(r0 + i) * H4;
#pragma unroll
            for (int j = 0; j < 16; ++j) cur[j] = Xr[lane + j * 64];
            float acc = 0.f;
#pragma unroll
            for (int j = 0; j < 16; ++j) {
                float4 x = cur[j];
                float4 vv = vsh[lane + j * 64];
                float4 cc = csh[lane + j * 64];
                acc += x.x * vv.x + x.y * vv.y + x.z * vv.z + x.w * vv.w;
                frob += x.x * x.x + x.y * x.y + x.z * x.z + x.w * x.w;
                mx = fmaxf(mx, fmaxf(fmaxf(fabsf(x.x), fabsf(x.y)),
                                     fmaxf(fabsf(x.z), fabsf(x.w))));
                float ax = x.x + (x.x * cc.x) * 0.5f;
                float ay = x.y + (x.y * cc.y) * 0.5f;
                float az = x.z + (x.z * cc.z) * 0.5f;
                float aw = x.w + (x.w * cc.w) * 0.5f;
                ma = fmaxf(ma, fmaxf(fmaxf(fabsf(ax), fabsf(ay)),
                                     fmaxf(fabsf(az), fabsf(aw))));
            }
            acc = wave_sum(acc);
#pragma unroll
            for (int j = 0; j < 16; ++j) {
                wa[j].x += acc * cur[j].x;
                wa[j].y += acc * cur[j].y;
                wa[j].z += acc * cur[j].z;
                wa[j].w += acc * cur[j].w;
            }
        }
#pragma unroll
        for (int m = 32; m; m >>= 1) {
            frob += __shfl_xor(frob, m);
            mx = fmaxf(mx, __shfl_xor(mx, m));
            ma = fmaxf(ma, __shfl_xor(ma, m));
        }
        if (lane == 0) { smn[wid] = frob; smn[4 + wid] = mx; smn[8 + wid] = ma; }
        flush_part(wa, wredA, wredB, part4 + (size_t)bid * H4, t, lane, wid);
    }
    grid.sync();  // ---- sync1 ----

    // ---------------- Stage B: merge stats; reduce part -> w1 ----------------
    if (t == 0) {
        atomicAdd(&scal[9], smn[0] + smn[1] + smn[2] + smn[3]);
        atomicMax(reinterpret_cast<unsigned*>(&scal[10]),
                  __float_as_uint(fmaxf(fmaxf(smn[4], smn[5]), fmaxf(smn[6], smn[7]))));
        atomicMax(reinterpret_cast<unsigned*>(&scal[11]),
                  __float_as_uint(fmaxf(fmaxf(smn[8], smn[9]), fmaxf(smn[10], smn[11]))));
    }
    {
        const float* part = reinterpret_cast<const float*>(part4);
        const int col = gtid & (HC - 1);
        const int chunk = gtid >> 12;  // 0..31
        float s = 0.f;
#pragma unroll
        for (int k = 0; k < 16; ++k) s += part[(size_t)(chunk * 16 + k) * HC + col];
        atomicAdd(&w1[col], s);
    }
    grid.sync();  // ---- sync2 ----

    // ---------------- Stage C: X^T (X w1/||w1||) ----------------
    {
        float ss = 0.f;
#pragma unroll
        for (int k = 0; k < 4; ++k) {
            int idx = t + k * TPB;
            float4 vv = reinterpret_cast<const float4*>(w1)[idx];
            vsh[idx] = vv;
            ss += vv.x * vv.x + vv.y * vv.y + vv.z * vv.z + vv.w * vv.w;
        }
        ss = wave_sum(ss);
        if (lane == 0) smn[wid] = ss;
        __syncthreads();
        const float inv = 1.0f / fmaxf(sqrtf(smn[0] + smn[1] + smn[2] + smn[3]), EPSV);

        float4 wa[16];
#pragma unroll
        for (int j = 0; j < 16; ++j) wa[j] = make_float4(0.f, 0.f, 0.f, 0.f);
        float4 cur[16];
#pragma unroll
        for (int i = 0; i < 4; ++i) {
            const float4* Xr = X4 + (size_t)(r0 + i) * H4;
#pragma unroll
            for (int j = 0; j < 16; ++j) cur[j] = Xr[lane + j * 64];
            float acc = 0.f;
#pragma unroll
            for (int j = 0; j < 16; ++j) {
                float4 x = cur[j];
                float4 vv = vsh[lane + j * 64];
                acc += x.x * vv.x + x.y * vv.y + x.z * vv.z + x.w * vv.w;
            }
            acc = wave_sum(acc) * inv;
#pragma unroll
            for (int j = 0; j < 16; ++j) {
                wa[j].x += acc * cur[j].x;
                wa[j].y += acc * cur[j].y;
                wa[j].z += acc * cur[j].z;
                wa[j].w += acc * cur[j].w;
            }
        }
        flush_part(wa, wredA, wredB, part4 + (size_t)bid * H4, t, lane, wid);
    }
    grid.sync();  // ---- sync3 ----

    // ---------------- Stage D: reduce part -> w2 ----------------
    {
        const float* part = reinterpret_cast<const float*>(part4);
        const int col = gtid & (HC - 1);
        const int chunk = gtid >> 12;
        float s = 0.f;
#pragma unroll
        for (int k = 0; k < 16; ++k) s += part[(size_t)(chunk * 16 + k) * HC + col];
        atomicAdd(&w2[col], s);
    }
    grid.sync();  // ---- sync4 ----

    // ---------------- Stage E: sigma^2 = ||X w2/||w2||||^2 ----------------
    {
        float ss = 0.f;
#pragma unroll
        for (int k = 0; k < 4; ++k) {
            int idx = t + k * TPB;
            float4 vv = reinterpret_cast<const float4*>(w2)[idx];
            vsh[idx] = vv;
            ss += vv.x * vv.x + vv.y * vv.y + vv.z * vv.z + vv.w * vv.w;
        }
        ss = wave_sum(ss);
        if (lane == 0) smn[wid] = ss;
        __syncthreads();
        const float inv = 1.0f / fmaxf(sqrtf(smn[0] + smn[1] + smn[2] + smn[3]), EPSV);
        float sig = 0.f;
#pragma unroll
        for (int i = 0; i < 4; ++i) {
            const float4* Xr = X4 + (size_t)(r0 + i) * H4;
            float acc = 0.f;
#pragma unroll
            for (int j = 0; j < 16; ++j) {
                float4 x = Xr[lane + j * 64];
                float4 vv = vsh[lane + j * 64];
                acc += x.x * vv.x + x.y * vv.y + x.z * vv.z + x.w * vv.w;
            }
            acc = wave_sum(acc) * inv;
            sig += acc * acc;
        }
        __syncthreads();
        if (lane == 0) smn[8 + wid] = sig;
        __syncthreads();
        if (t == 0) atomicAdd(&scal[8], smn[8] + smn[9] + smn[10] + smn[11]);
    }
    grid.sync();  // ---- sync5 ----

    // ---------------- Stage F: finalize + fake-quant ----------------
    {
        const float sig2 = scal[8];
        const float fr = scal[9];
        const float score = sig2 / (fr + EPSV);
        const bool flag = score > 0.35f;
        const unsigned mb = reinterpret_cast<const unsigned*>(scal)[flag ? 11 : 10];
        const float mv = __uint_as_float(mb);
        const float scale = (mv < EPSV) ? 1.0f : mv / 7.0f;
        const size_t total4 = (size_t)NR * HC / 4;
        for (size_t i = (size_t)gtid; i < total4; i += STRIDE) {
            float4 x = X4[i];
            if (flag) {
                float4 cc = csh[(int)(i & (H4 - 1))];
                x.x += (x.x * cc.x) * 0.5f;
                x.y += (x.y * cc.y) * 0.5f;
                x.z += (x.z * cc.z) * 0.5f;
                x.w += (x.w * cc.w) * 0.5f;
            }
            float4 o;
            o.x = fminf(fmaxf(rintf(x.x / scale), -8.f), 7.f) * scale;
            o.y = fminf(fmaxf(rintf(x.y / scale), -8.f), 7.f) * scale;
            o.z = fminf(fmaxf(rintf(x.z / scale), -8.f), 7.f) * scale;
            o.w = fminf(fmaxf(rintf(x.w / scale), -8.f), 7.f) * scale;
            out4[i] = o;
        }
    }
}

// ================= Fallback (R2 pipeline) if cooperative launch fails ===========

__global__ void compute_c_kernel(const float* __restrict__ a, const float* __restrict__ b,
                                 float* __restrict__ c) {
    int i = blockIdx.x * blockDim.x + threadIdx.x;
    if (i < HC) c[i] = a[i] * b[i];
}

template <int NORMIN>
__global__ __launch_bounds__(256, 1) void xtxv_kernel(
    const float4* __restrict__ X4, const float4* __restrict__ vin,
    float4* __restrict__ part4) {
    __shared__ float4 vsh[H4];
    __shared__ float4 wredA[H4];
    __shared__ float4 wredB[H4];
    __shared__ float smn[4];
    const int t = threadIdx.x;
    const int lane = t & 63;
    const int wid = t >> 6;
    float ss = 0.f;
#pragma unroll
    for (int k = 0; k < 4; ++k) {
        float4 vv = vin[t + k * 256];
        vsh[t + k * 256] = vv;
        if (NORMIN) ss += vv.x * vv.x + vv.y * vv.y + vv.z * vv.z + vv.w * vv.w;
    }
    if (NORMIN) {
        ss = wave_sum(ss);
        if (lane == 0) smn[wid] = ss;
    }
    __syncthreads();
    float inv = 1.0f;
    if (NORMIN) inv = 1.0f / fmaxf(sqrtf(smn[0] + smn[1] + smn[2] + smn[3]), EPSV);
    float4 wa[16];
#pragma unroll
    for (int j = 0; j < 16; ++j) wa[j] = make_float4(0.f, 0.f, 0.f, 0.f);
    const int r0 = blockIdx.x * 16 + wid * 4;
    float4 cur[16];
#pragma unroll
    for (int i = 0; i < 4; ++i) {
        const float4* Xr = X4 + (size_t)(r0 + i) * H4;
#pragma unroll
        for (int j = 0; j < 16; ++j) cur[j] = Xr[lane + j * 64];
        float acc = 0.f;
#pragma unroll
        for (int j = 0; j < 16; ++j) {
            float4 x = cur[j];
            float4 vv = vsh[lane + j * 64];
            acc += x.x * vv.x + x.y * vv.y + x.z * vv.z + x.w * vv.w;
        }
        acc = wave_sum(acc) * inv;
#pragma unroll
        for (int j = 0; j < 16; ++j) {
            wa[j].x += acc * cur[j].x;
            wa[j].y += acc * cur[j].y;
            wa[j].z += acc * cur[j].z;
            wa[j].w += acc * cur[j].w;
        }
    }
    flush_part(wa, wredA, wredB, part4 + (size_t)blockIdx.x * H4, t, lane, wid);
}

__global__ __launch_bounds__(256) void reduce_part_kernel(
    const float* __restrict__ part, float* __restrict__ w) {
    const int g = blockIdx.x * 256 + threadIdx.x;
    const int h = g & (HC - 1);
    const int chunk = g >> 12;
    float s = 0.f;
#pragma unroll 8
    for (int b = chunk * 16; b < chunk * 16 + 16; ++b) s += part[(size_t)b * HC + h];
    atomicAdd(&w[h], s);
}

__global__ __launch_bounds__(256, 1) void rowsig_kernel(
    const float4* __restrict__ X4, const float4* __restrict__ vin,
    const float4* __restrict__ c4, float* __restrict__ scal) {
    __shared__ float4 vsh[H4];
    __shared__ float4 csh[H4];
    __shared__ float smn[4];
    __shared__ float sm[16];
    const int t = threadIdx.x;
    const int lane = t & 63;
    const int wid = t >> 6;
    float ss = 0.f;
#pragma unroll
    for (int k = 0; k < 4; ++k) {
        float4 vv = vin[t + k * 256];
        vsh[t + k * 256] = vv;
        csh[t + k * 256] = c4[t + k * 256];
        ss += vv.x * vv.x + vv.y * vv.y + vv.z * vv.z + vv.w * vv.w;
    }
    ss = wave_sum(ss);
    if (lane == 0) smn[wid] = ss;
    __syncthreads();
    const float inv = 1.0f / fmaxf(sqrtf(smn[0] + smn[1] + smn[2] + smn[3]), EPSV);
    const int r0 = blockIdx.x * 16 + wid * 4;
    float sig = 0.f, frob = 0.f, mx = 0.f, ma = 0.f;
#pragma unroll
    for (int i = 0; i < 4; ++i) {
        const float4* Xr = X4 + (size_t)(r0 + i) * H4;
        float acc = 0.f;
#pragma unroll
        for (int j = 0; j < 16; ++j) {
            float4 x = Xr[lane + j * 64];
            float4 vv = vsh[lane + j * 64];
            float4 cc = csh[lane + j * 64];
            acc += x.x * vv.x + x.y * vv.y + x.z * vv.z + x.w * vv.w;
            frob += x.x * x.x + x.y * x.y + x.z * x.z + x.w * x.w;
            mx = fmaxf(mx, fmaxf(fmaxf(fabsf(x.x), fabsf(x.y)),
                                 fmaxf(fabsf(x.z), fabsf(x.w))));
            float ax = x.x + (x.x * cc.x) * 0.5f;
            float ay = x.y + (x.y * cc.y) * 0.5f;
            float az = x.z + (x.z * cc.z) * 0.5f;
            float aw = x.w + (x.w * cc.w) * 0.5f;
            ma = fmaxf(ma, fmaxf(fmaxf(fabsf(ax), fabsf(ay)),
                                 fmaxf(fabsf(az), fabsf(aw))));
        }
        acc = wave_sum(acc) * inv;
        sig += acc * acc;
    }
#pragma unroll
    for (int m = 32; m; m >>= 1) {
        frob += __shfl_xor(frob, m);
        mx = fmaxf(mx, __shfl_xor(mx, m));
        ma = fmaxf(ma, __shfl_xor(ma, m));
    }
    if (lane == 0) {
        sm[wid] = frob; sm[4 + wid] = mx; sm[8 + wid] = ma; sm[12 + wid] = sig;
    }
    __syncthreads();
    if (t == 0) {
        atomicAdd(&scal[9], sm[0] + sm[1] + sm[2] + sm[3]);
        atomicAdd(&scal[8], sm[12] + sm[13] + sm[14] + sm[15]);
        atomicMax(reinterpret_cast<unsigned*>(&scal[10]),
                  __float_as_uint(fmaxf(fmaxf(sm[4], sm[5]), fmaxf(sm[6], sm[7]))));
        atomicMax(reinterpret_cast<unsigned*>(&scal[11]),
                  __float_as_uint(fmaxf(fmaxf(sm[8], sm[9]), fmaxf(sm[10], sm[11]))));
    }
}

__global__ void finalize_kernel(float* __restrict__ scal) {
    float score = scal[8] / (scal[9] + EPSV);
    int flag = score > 0.35f ? 1 : 0;
    float mv = __uint_as_float(reinterpret_cast<unsigned*>(scal)[flag ? 11 : 10]);
    scal[12] = (mv < EPSV) ? 1.0f : mv / 7.0f;
    scal[13] = (float)flag;
}

__global__ __launch_bounds__(256) void quant_kernel(
    const float* __restrict__ X, const float* __restrict__ c,
    const float* __restrict__ scal, float* __restrict__ out) {
    const float scale = scal[12];
    const bool flag = scal[13] != 0.0f;
    const size_t total4 = (size_t)NR * HC / 4;
    const float4* X4 = reinterpret_cast<const float4*>(X);
    const float4* C4 = reinterpret_cast<const float4*>(c);
    float4* O4 = reinterpret_cast<float4*>(out);
    for (size_t i = (size_t)blockIdx.x * blockDim.x + threadIdx.x; i < total4;
         i += (size_t)gridDim.x * blockDim.x) {
        float4 x = X4[i];
        if (flag) {
            float4 cc = C4[i & (H4 - 1)];
            x.x += (x.x * cc.x) * 0.5f;
            x.y += (x.y * cc.y) * 0.5f;
            x.z += (x.z * cc.z) * 0.5f;
            x.w += (x.w * cc.w) * 0.5f;
        }
        float4 o;
        o.x = fminf(fmaxf(rintf(x.x / scale), -8.f), 7.f) * scale;
        o.y = fminf(fmaxf(rintf(x.y / scale), -8.f), 7.f) * scale;
        o.z = fminf(fmaxf(rintf(x.z / scale), -8.f), 7.f) * scale;
        o.w = fminf(fmaxf(rintf(x.w / scale), -8.f), 7.f) * scale;
        O4[i] = o;
    }
}

extern "C" void kernel_launch(void* const* d_in, const int* in_sizes, int n_in,
                              void* d_out, int out_size, void* d_ws, size_t ws_size,
                              hipStream_t stream) {
    const float4* X4 = reinterpret_cast<const float4*>(d_in[0]);
    const float* la = (const float*)d_in[1];
    const float* lb = (const float*)d_in[2];
    const float4* v04 = reinterpret_cast<const float4*>(d_in[3]);
    float* ws = (float*)d_ws;
    float* w1 = ws;
    float* w2 = ws + HC;
    float* scal = ws + 2 * HC;
    float* cbuf = ws + 2 * HC + 16;  // fallback's c vector
    float4* part4 = reinterpret_cast<float4*>(d_out);
    float4* out4 = reinterpret_cast<float4*>(d_out);

    void* args[] = {(void*)&X4, (void*)&la, (void*)&lb,   (void*)&v04, (void*)&w1,
                    (void*)&w2, (void*)&scal, (void*)&part4, (void*)&out4};
    hipError_t err = hipLaunchCooperativeKernel(
        reinterpret_cast<void*>(mega_kernel), dim3(NB), dim3(TPB), args, 0, stream);
    if (err == hipSuccess) return;

    // -------- fallback: R2 multi-kernel pipeline --------
    const float* X = (const float*)d_in[0];
    float* out = (float*)d_out;
    float* part = (float*)d_out;
    hipMemsetAsync(w1, 0, 2 * HC * sizeof(float), stream);
    hipMemsetAsync(scal, 0, 16 * sizeof(float), stream);
    compute_c_kernel<<<HC / 256, 256, 0, stream>>>(la, lb, cbuf);
    xtxv_kernel<0><<<NB, 256, 0, stream>>>(X4, v04, part4);
    reduce_part_kernel<<<512, 256, 0, stream>>>(part, w1);
    xtxv_kernel<1><<<NB, 256, 0, stream>>>(X4, reinterpret_cast<const float4*>(w1), part4);
    reduce_part_kernel<<<512, 256, 0, stream>>>(part, w2);
    rowsig_kernel<<<NB, 256, 0, stream>>>(X4, reinterpret_cast<const float4*>(w2),
                                          reinterpret_cast<const float4*>(cbuf), scal);
    finalize_kernel<<<1, 1, 0, stream>>>(scal);
    quant_kernel<<<2048, 256, 0, stream>>>(X, cbuf, scal, out);
}

// Round 4
// 190.249 us; speedup vs baseline: 3.7090x; 3.7090x over previous
//
#include <hip/hip_runtime.h>

// DynamicQuantizer: power-iteration score -> conditional rank-1 scale -> int4 fake-quant.
// X: [8192, 4096] f32. Output f32 same shape.
//
// Pipeline (3 X reads + 1 write; optimistic quant, fixup only if flag==1):
//   1. memset ws (w1,w2,scal)
//   2. xtxv<0,1>: part = per-block X^T (X v0); fused frob, max|X|, max|X_adapt|
//   3. reduce part -> w1
//   4. xtxv<1,0>: part = per-block X^T (X w1/||w1||)
//   5. reduce part -> w2
//   6. quantsig: sigma^2 = ||X w2/||w2||||^2 AND out = quant(X, max|X|/7) (flag-0 branch),
//                X row loaded once into registers, used for both.
//   7. finalize: flag = score>0.35; final scale -> scal[12..13]
//   8. fixup: early-exit if flag==0; else re-quant with adapted values (exact flag-1 branch)
//
// ws (floats): [0,4096) w1 | [4096,8192) w2 | [8192,8208) scal
//   scal: 8 sigma_sq, 9 frob, 10 max|X| bits, 11 max|X_adapt| bits, 12 scale, 13 flag
// d_out doubles as the 512x4096 partial buffer until quantsig overwrites it.

#define NR 8192
#define HC 4096
#define H4 (HC / 4)
#define EPSV 1e-8f
#define NB 512

__device__ __forceinline__ float wave_sum(float v) {
#pragma unroll
    for (int m = 32; m; m >>= 1) v += __shfl_xor(v, m);
    return v;
}

__device__ __forceinline__ void flush_part(const float4 (&wa)[16], float4* wredA,
                                           float4* wredB, float4* dst, int t, int lane,
                                           int wid) {
    if (wid == 0) {
#pragma unroll
        for (int j = 0; j < 16; ++j) wredA[j * 64 + lane] = wa[j];
    } else if (wid == 1) {
#pragma unroll
        for (int j = 0; j < 16; ++j) wredB[j * 64 + lane] = wa[j];
    }
    __syncthreads();
    if (wid == 2) {
#pragma unroll
        for (int j = 0; j < 16; ++j) {
            float4 a = wredA[j * 64 + lane];
            a.x += wa[j].x; a.y += wa[j].y; a.z += wa[j].z; a.w += wa[j].w;
            wredA[j * 64 + lane] = a;
        }
    } else if (wid == 3) {
#pragma unroll
        for (int j = 0; j < 16; ++j) {
            float4 b = wredB[j * 64 + lane];
            b.x += wa[j].x; b.y += wa[j].y; b.z += wa[j].z; b.w += wa[j].w;
            wredB[j * 64 + lane] = b;
        }
    }
    __syncthreads();
#pragma unroll
    for (int k = 0; k < 4; ++k) {
        float4 a = wredA[t + k * 256];
        float4 b = wredB[t + k * 256];
        a.x += b.x; a.y += b.y; a.z += b.z; a.w += b.w;
        dst[t + k * 256] = a;
    }
}

// Per-block partial of X^T (X v * inv) over 16 rows (4 rows/wave, row register-resident).
// STATS: fuse frob, max|X|, max|X_adapt| (c = la*lb staged inline).
// NORMIN: inv = 1/max(||v||,eps) computed in-block from staged v.
template <int NORMIN, int STATS>
__global__ __launch_bounds__(256, 1) void xtxv_kernel(
    const float4* __restrict__ X4, const float4* __restrict__ vin,
    const float4* __restrict__ la4, const float4* __restrict__ lb4,
    float4* __restrict__ part4, float* __restrict__ scal) {
    __shared__ float4 vsh[H4];    // 16 KB staged v
    __shared__ float4 csh[H4];    // 16 KB c (STATS only; allocated anyway)
    __shared__ float4 wredA[H4];  // 16 KB
    __shared__ float4 wredB[H4];  // 16 KB
    __shared__ float smn[16];
    const int t = threadIdx.x;
    const int lane = t & 63;
    const int wid = t >> 6;

    float ss = 0.f;
#pragma unroll
    for (int k = 0; k < 4; ++k) {
        int idx = t + k * 256;
        float4 vv = vin[idx];
        vsh[idx] = vv;
        if (STATS) {
            float4 A = la4[idx];
            float4 B = lb4[idx];
            csh[idx] = make_float4(A.x * B.x, A.y * B.y, A.z * B.z, A.w * B.w);
        }
        if (NORMIN) ss += vv.x * vv.x + vv.y * vv.y + vv.z * vv.z + vv.w * vv.w;
    }
    if (NORMIN) {
        ss = wave_sum(ss);
        if (lane == 0) smn[wid] = ss;
    }
    __syncthreads();
    float inv = 1.0f;
    if (NORMIN) inv = 1.0f / fmaxf(sqrtf(smn[0] + smn[1] + smn[2] + smn[3]), EPSV);

    float4 wa[16];
#pragma unroll
    for (int j = 0; j < 16; ++j) wa[j] = make_float4(0.f, 0.f, 0.f, 0.f);
    const int r0 = blockIdx.x * 16 + wid * 4;
    float frob = 0.f, mx = 0.f, ma = 0.f;
    float4 cur[16];
#pragma unroll
    for (int i = 0; i < 4; ++i) {
        const float4* Xr = X4 + (size_t)(r0 + i) * H4;
#pragma unroll
        for (int j = 0; j < 16; ++j) cur[j] = Xr[lane + j * 64];
        float acc = 0.f;
#pragma unroll
        for (int j = 0; j < 16; ++j) {
            float4 x = cur[j];
            float4 vv = vsh[lane + j * 64];
            acc += x.x * vv.x + x.y * vv.y + x.z * vv.z + x.w * vv.w;
            if (STATS) {
                float4 cc = csh[lane + j * 64];
                frob += x.x * x.x + x.y * x.y + x.z * x.z + x.w * x.w;
                mx = fmaxf(mx, fmaxf(fmaxf(fabsf(x.x), fabsf(x.y)),
                                     fmaxf(fabsf(x.z), fabsf(x.w))));
                float ax = x.x + (x.x * cc.x) * 0.5f;
                float ay = x.y + (x.y * cc.y) * 0.5f;
                float az = x.z + (x.z * cc.z) * 0.5f;
                float aw = x.w + (x.w * cc.w) * 0.5f;
                ma = fmaxf(ma, fmaxf(fmaxf(fabsf(ax), fabsf(ay)),
                                     fmaxf(fabsf(az), fabsf(aw))));
            }
        }
        acc = wave_sum(acc) * inv;
#pragma unroll
        for (int j = 0; j < 16; ++j) {
            wa[j].x += acc * cur[j].x;
            wa[j].y += acc * cur[j].y;
            wa[j].z += acc * cur[j].z;
            wa[j].w += acc * cur[j].w;
        }
    }
    if (STATS) {
#pragma unroll
        for (int m = 32; m; m >>= 1) {
            frob += __shfl_xor(frob, m);
            mx = fmaxf(mx, __shfl_xor(mx, m));
            ma = fmaxf(ma, __shfl_xor(ma, m));
        }
        if (lane == 0) { smn[4 + wid] = frob; smn[8 + wid] = mx; smn[12 + wid] = ma; }
    }
    flush_part(wa, wredA, wredB, part4 + (size_t)blockIdx.x * H4, t, lane, wid);
    if (STATS && t == 0) {
        atomicAdd(&scal[9], smn[4] + smn[5] + smn[6] + smn[7]);
        atomicMax(reinterpret_cast<unsigned*>(&scal[10]),
                  __float_as_uint(fmaxf(fmaxf(smn[8], smn[9]), fmaxf(smn[10], smn[11]))));
        atomicMax(reinterpret_cast<unsigned*>(&scal[11]),
                  __float_as_uint(fmaxf(fmaxf(smn[12], smn[13]), fmaxf(smn[14], smn[15]))));
    }
}

// w[h] += partial column sums of part[512][HC].
__global__ __launch_bounds__(256) void reduce_part_kernel(
    const float* __restrict__ part, float* __restrict__ w) {
    const int g = blockIdx.x * 256 + threadIdx.x;  // 512 blocks -> 131072 threads
    const int h = g & (HC - 1);
    const int chunk = g >> 12;  // 0..31
    float s = 0.f;
#pragma unroll
    for (int k = 0; k < 16; ++k) s += part[(size_t)(chunk * 16 + k) * HC + h];
    atomicAdd(&w[h], s);
}

// sigma^2 accumulation AND optimistic quant (flag-0 scale) in one X read.
__global__ __launch_bounds__(256, 2) void quantsig_kernel(
    const float4* __restrict__ X4, const float4* __restrict__ w24,
    float* __restrict__ scal, float4* __restrict__ out4) {
    __shared__ float4 vsh[H4];
    __shared__ float smn[16];
    const int t = threadIdx.x;
    const int lane = t & 63;
    const int wid = t >> 6;

    const float mv = __uint_as_float(reinterpret_cast<const unsigned*>(scal)[10]);
    const float scale0 = (mv < EPSV) ? 1.0f : mv / 7.0f;

    float ss = 0.f;
#pragma unroll
    for (int k = 0; k < 4; ++k) {
        int idx = t + k * 256;
        float4 vv = w24[idx];
        vsh[idx] = vv;
        ss += vv.x * vv.x + vv.y * vv.y + vv.z * vv.z + vv.w * vv.w;
    }
    ss = wave_sum(ss);
    if (lane == 0) smn[wid] = ss;
    __syncthreads();
    const float inv = 1.0f / fmaxf(sqrtf(smn[0] + smn[1] + smn[2] + smn[3]), EPSV);

    const int r0 = blockIdx.x * 16 + wid * 4;
    float sig = 0.f;
    float4 cur[16];
#pragma unroll
    for (int i = 0; i < 4; ++i) {
        const float4* Xr = X4 + (size_t)(r0 + i) * H4;
#pragma unroll
        for (int j = 0; j < 16; ++j) cur[j] = Xr[lane + j * 64];
        float acc = 0.f;
#pragma unroll
        for (int j = 0; j < 16; ++j) {
            float4 x = cur[j];
            float4 vv = vsh[lane + j * 64];
            acc += x.x * vv.x + x.y * vv.y + x.z * vv.z + x.w * vv.w;
        }
        acc = wave_sum(acc) * inv;
        sig += acc * acc;
        float4* Or = out4 + (size_t)(r0 + i) * H4;
#pragma unroll
        for (int j = 0; j < 16; ++j) {
            float4 x = cur[j];
            float4 o;
            o.x = fminf(fmaxf(rintf(x.x / scale0), -8.f), 7.f) * scale0;
            o.y = fminf(fmaxf(rintf(x.y / scale0), -8.f), 7.f) * scale0;
            o.z = fminf(fmaxf(rintf(x.z / scale0), -8.f), 7.f) * scale0;
            o.w = fminf(fmaxf(rintf(x.w / scale0), -8.f), 7.f) * scale0;
            Or[lane + j * 64] = o;
        }
    }
    if (lane == 0) smn[8 + wid] = sig;
    __syncthreads();
    if (t == 0) atomicAdd(&scal[8], smn[8] + smn[9] + smn[10] + smn[11]);
}

__global__ void finalize_kernel(float* __restrict__ scal) {
    float score = scal[8] / (scal[9] + EPSV);
    int flag = score > 0.35f ? 1 : 0;
    float mv = __uint_as_float(reinterpret_cast<unsigned*>(scal)[flag ? 11 : 10]);
    scal[12] = (mv < EPSV) ? 1.0f : mv / 7.0f;
    scal[13] = (float)flag;
}

// Only does work when flag==1: re-quant with the adapted values (exact flag-1 branch).
__global__ __launch_bounds__(256) void fixup_kernel(
    const float4* __restrict__ X4, const float4* __restrict__ la4,
    const float4* __restrict__ lb4, const float* __restrict__ scal,
    float4* __restrict__ out4) {
    if (scal[13] == 0.0f) return;
    const float scale = scal[12];
    const size_t total4 = (size_t)NR * HC / 4;
    for (size_t i = (size_t)blockIdx.x * blockDim.x + threadIdx.x; i < total4;
         i += (size_t)gridDim.x * blockDim.x) {
        float4 x = X4[i];
        int h = (int)(i & (H4 - 1));
        float4 A = la4[h];
        float4 B = lb4[h];
        x.x += (x.x * (A.x * B.x)) * 0.5f;
        x.y += (x.y * (A.y * B.y)) * 0.5f;
        x.z += (x.z * (A.z * B.z)) * 0.5f;
        x.w += (x.w * (A.w * B.w)) * 0.5f;
        float4 o;
        o.x = fminf(fmaxf(rintf(x.x / scale), -8.f), 7.f) * scale;
        o.y = fminf(fmaxf(rintf(x.y / scale), -8.f), 7.f) * scale;
        o.z = fminf(fmaxf(rintf(x.z / scale), -8.f), 7.f) * scale;
        o.w = fminf(fmaxf(rintf(x.w / scale), -8.f), 7.f) * scale;
        out4[i] = o;
    }
}

extern "C" void kernel_launch(void* const* d_in, const int* in_sizes, int n_in,
                              void* d_out, int out_size, void* d_ws, size_t ws_size,
                              hipStream_t stream) {
    const float4* X4 = reinterpret_cast<const float4*>(d_in[0]);
    const float4* la4 = reinterpret_cast<const float4*>(d_in[1]);
    const float4* lb4 = reinterpret_cast<const float4*>(d_in[2]);
    const float4* v04 = reinterpret_cast<const float4*>(d_in[3]);
    float* ws = (float*)d_ws;
    float* w1 = ws;
    float* w2 = ws + HC;
    float* scal = ws + 2 * HC;
    float4* part4 = reinterpret_cast<float4*>(d_out);
    float4* out4 = reinterpret_cast<float4*>(d_out);
    const float* part = (const float*)d_out;

    // zero w1 + w2 + scal in one memset
    hipMemsetAsync(ws, 0, (2 * HC + 16) * sizeof(float), stream);

    // power iteration 1 (+ frob, max|X|, max|X_adapt|)
    xtxv_kernel<0, 1><<<NB, 256, 0, stream>>>(X4, v04, la4, lb4, part4, scal);
    reduce_part_kernel<<<NB, 256, 0, stream>>>(part, w1);

    // power iteration 2
    xtxv_kernel<1, 0><<<NB, 256, 0, stream>>>(X4, reinterpret_cast<const float4*>(w1),
                                              la4, lb4, part4, scal);
    reduce_part_kernel<<<NB, 256, 0, stream>>>(part, w2);

    // sigma^2 + optimistic quant in one pass (overwrites partial scratch)
    quantsig_kernel<<<NB, 256, 0, stream>>>(X4, reinterpret_cast<const float4*>(w2),
                                            scal, out4);
    finalize_kernel<<<1, 1, 0, stream>>>(scal);

    // re-quant only if the adapted branch was taken
    fixup_kernel<<<NB, 256, 0, stream>>>(X4, la4, lb4, scal, out4);
}

// Round 5
// 134.883 us; speedup vs baseline: 5.2315x; 1.4105x over previous
//
#include <hip/hip_runtime.h>

// DynamicQuantizer: power-iteration score -> conditional rank-1 scale -> int4 fake-quant.
// X: [8192, 4096] f32. Output f32 same shape.
//
// Pipeline (3 X reads + 1 write on the hot path):
//   1. memset ws (w1,w2,scal)
//   2. xtxv<0,1>: part = per-block X^T (X v0); fused frob + max|X| (scalars only — the
//      max|X_adapt| chain and c-staging spilled cur[16] to scratch in R4: WRITE 40 MB)
//   3. reduce part -> w1
//   4. xtxv<1,0>: part = per-block X^T (X w1/||w1||)
//   5. reduce part -> w2
//   6. quantsig: sigma^2 = ||X w2/||w2||||^2 AND out = quant(X, max|X|/7) in one X read
//   7. fixup_max: early-exit if score<=0.35; else max|X_adapt| -> scal[11]
//   8. fixup_quant: early-exit if score<=0.35; else re-quant (exact flag-1 branch)
//
// ws (floats): [0,4096) w1 | [4096,8192) w2 | [8192,8208) scal
//   scal: 8 sigma_sq, 9 frob, 10 max|X| bits, 11 max|X_adapt| bits
// d_out doubles as the 512x4096 partial buffer until quantsig overwrites it.

#define NR 8192
#define HC 4096
#define H4 (HC / 4)
#define EPSV 1e-8f
#define NB 512

__device__ __forceinline__ float wave_sum(float v) {
#pragma unroll
    for (int m = 32; m; m >>= 1) v += __shfl_xor(v, m);
    return v;
}

__device__ __forceinline__ void flush_part(const float4 (&wa)[16], float4* wredA,
                                           float4* wredB, float4* dst, int t, int lane,
                                           int wid) {
    if (wid == 0) {
#pragma unroll
        for (int j = 0; j < 16; ++j) wredA[j * 64 + lane] = wa[j];
    } else if (wid == 1) {
#pragma unroll
        for (int j = 0; j < 16; ++j) wredB[j * 64 + lane] = wa[j];
    }
    __syncthreads();
    if (wid == 2) {
#pragma unroll
        for (int j = 0; j < 16; ++j) {
            float4 a = wredA[j * 64 + lane];
            a.x += wa[j].x; a.y += wa[j].y; a.z += wa[j].z; a.w += wa[j].w;
            wredA[j * 64 + lane] = a;
        }
    } else if (wid == 3) {
#pragma unroll
        for (int j = 0; j < 16; ++j) {
            float4 b = wredB[j * 64 + lane];
            b.x += wa[j].x; b.y += wa[j].y; b.z += wa[j].z; b.w += wa[j].w;
            wredB[j * 64 + lane] = b;
        }
    }
    __syncthreads();
#pragma unroll
    for (int k = 0; k < 4; ++k) {
        float4 a = wredA[t + k * 256];
        float4 b = wredB[t + k * 256];
        a.x += b.x; a.y += b.y; a.z += b.z; a.w += b.w;
        dst[t + k * 256] = a;
    }
}

// Per-block partial of X^T (X v * inv) over 16 rows (4 rows/wave, row register-resident).
// STATS: fuse frob + max|X| (scalar accumulators only — keep register pressure low).
// NORMIN: inv = 1/max(||v||,eps) computed in-block from staged v.
template <int NORMIN, int STATS>
__global__ __launch_bounds__(256, 1) void xtxv_kernel(
    const float4* __restrict__ X4, const float4* __restrict__ vin,
    float4* __restrict__ part4, float* __restrict__ scal) {
    __shared__ float4 vsh[H4];    // 16 KB staged v
    __shared__ float4 wredA[H4];  // 16 KB
    __shared__ float4 wredB[H4];  // 16 KB
    __shared__ float smn[12];
    const int t = threadIdx.x;
    const int lane = t & 63;
    const int wid = t >> 6;

    float ss = 0.f;
#pragma unroll
    for (int k = 0; k < 4; ++k) {
        int idx = t + k * 256;
        float4 vv = vin[idx];
        vsh[idx] = vv;
        if (NORMIN) ss += vv.x * vv.x + vv.y * vv.y + vv.z * vv.z + vv.w * vv.w;
    }
    if (NORMIN) {
        ss = wave_sum(ss);
        if (lane == 0) smn[wid] = ss;
    }
    __syncthreads();
    float inv = 1.0f;
    if (NORMIN) inv = 1.0f / fmaxf(sqrtf(smn[0] + smn[1] + smn[2] + smn[3]), EPSV);

    float4 wa[16];
#pragma unroll
    for (int j = 0; j < 16; ++j) wa[j] = make_float4(0.f, 0.f, 0.f, 0.f);
    const int r0 = blockIdx.x * 16 + wid * 4;
    float frob = 0.f, mx = 0.f;
    float4 cur[16];
#pragma unroll
    for (int i = 0; i < 4; ++i) {
        const float4* Xr = X4 + (size_t)(r0 + i) * H4;
#pragma unroll
        for (int j = 0; j < 16; ++j) cur[j] = Xr[lane + j * 64];
        float acc = 0.f;
#pragma unroll
        for (int j = 0; j < 16; ++j) {
            float4 x = cur[j];
            float4 vv = vsh[lane + j * 64];
            acc += x.x * vv.x + x.y * vv.y + x.z * vv.z + x.w * vv.w;
            if (STATS) {
                frob += x.x * x.x + x.y * x.y + x.z * x.z + x.w * x.w;
                mx = fmaxf(mx, fmaxf(fmaxf(fabsf(x.x), fabsf(x.y)),
                                     fmaxf(fabsf(x.z), fabsf(x.w))));
            }
        }
        acc = wave_sum(acc) * inv;
#pragma unroll
        for (int j = 0; j < 16; ++j) {
            wa[j].x += acc * cur[j].x;
            wa[j].y += acc * cur[j].y;
            wa[j].z += acc * cur[j].z;
            wa[j].w += acc * cur[j].w;
        }
    }
    if (STATS) {
#pragma unroll
        for (int m = 32; m; m >>= 1) {
            frob += __shfl_xor(frob, m);
            mx = fmaxf(mx, __shfl_xor(mx, m));
        }
        if (lane == 0) { smn[4 + wid] = frob; smn[8 + wid] = mx; }
    }
    flush_part(wa, wredA, wredB, part4 + (size_t)blockIdx.x * H4, t, lane, wid);
    if (STATS && t == 0) {
        atomicAdd(&scal[9], smn[4] + smn[5] + smn[6] + smn[7]);
        atomicMax(reinterpret_cast<unsigned*>(&scal[10]),
                  __float_as_uint(fmaxf(fmaxf(smn[8], smn[9]), fmaxf(smn[10], smn[11]))));
    }
}

// w[h] += partial column sums of part[512][HC].
__global__ __launch_bounds__(256) void reduce_part_kernel(
    const float* __restrict__ part, float* __restrict__ w) {
    const int g = blockIdx.x * 256 + threadIdx.x;  // 512 blocks -> 131072 threads
    const int h = g & (HC - 1);
    const int chunk = g >> 12;  // 0..31
    float s = 0.f;
#pragma unroll
    for (int k = 0; k < 16; ++k) s += part[(size_t)(chunk * 16 + k) * HC + h];
    atomicAdd(&w[h], s);
}

// sigma^2 accumulation AND optimistic quant (flag-0 scale) in one X read.
__global__ __launch_bounds__(256, 2) void quantsig_kernel(
    const float4* __restrict__ X4, const float4* __restrict__ w24,
    float* __restrict__ scal, float4* __restrict__ out4) {
    __shared__ float4 vsh[H4];
    __shared__ float smn[16];
    const int t = threadIdx.x;
    const int lane = t & 63;
    const int wid = t >> 6;

    const float mv = __uint_as_float(reinterpret_cast<const unsigned*>(scal)[10]);
    const float scale0 = (mv < EPSV) ? 1.0f : mv / 7.0f;

    float ss = 0.f;
#pragma unroll
    for (int k = 0; k < 4; ++k) {
        int idx = t + k * 256;
        float4 vv = w24[idx];
        vsh[idx] = vv;
        ss += vv.x * vv.x + vv.y * vv.y + vv.z * vv.z + vv.w * vv.w;
    }
    ss = wave_sum(ss);
    if (lane == 0) smn[wid] = ss;
    __syncthreads();
    const float inv = 1.0f / fmaxf(sqrtf(smn[0] + smn[1] + smn[2] + smn[3]), EPSV);

    const int r0 = blockIdx.x * 16 + wid * 4;
    float sig = 0.f;
    float4 cur[16];
#pragma unroll
    for (int i = 0; i < 4; ++i) {
        const float4* Xr = X4 + (size_t)(r0 + i) * H4;
#pragma unroll
        for (int j = 0; j < 16; ++j) cur[j] = Xr[lane + j * 64];
        float acc = 0.f;
#pragma unroll
        for (int j = 0; j < 16; ++j) {
            float4 x = cur[j];
            float4 vv = vsh[lane + j * 64];
            acc += x.x * vv.x + x.y * vv.y + x.z * vv.z + x.w * vv.w;
        }
        acc = wave_sum(acc) * inv;
        sig += acc * acc;
        float4* Or = out4 + (size_t)(r0 + i) * H4;
#pragma unroll
        for (int j = 0; j < 16; ++j) {
            float4 x = cur[j];
            float4 o;
            o.x = fminf(fmaxf(rintf(x.x / scale0), -8.f), 7.f) * scale0;
            o.y = fminf(fmaxf(rintf(x.y / scale0), -8.f), 7.f) * scale0;
            o.z = fminf(fmaxf(rintf(x.z / scale0), -8.f), 7.f) * scale0;
            o.w = fminf(fmaxf(rintf(x.w / scale0), -8.f), 7.f) * scale0;
            Or[lane + j * 64] = o;
        }
    }
    if (lane == 0) smn[8 + wid] = sig;
    __syncthreads();
    if (t == 0) atomicAdd(&scal[8], smn[8] + smn[9] + smn[10] + smn[11]);
}

// flag==1 only: compute max|X_adapt| -> scal[11]. Early-exits otherwise.
__global__ __launch_bounds__(256) void fixup_max_kernel(
    const float4* __restrict__ X4, const float4* __restrict__ la4,
    const float4* __restrict__ lb4, float* __restrict__ scal) {
    if (!(scal[8] / (scal[9] + EPSV) > 0.35f)) return;
    __shared__ float sm[4];
    const int t = threadIdx.x;
    const int lane = t & 63;
    const int wid = t >> 6;
    float ma = 0.f;
    const size_t total4 = (size_t)NR * HC / 4;
    for (size_t i = (size_t)blockIdx.x * blockDim.x + t; i < total4;
         i += (size_t)gridDim.x * blockDim.x) {
        float4 x = X4[i];
        int h = (int)(i & (H4 - 1));
        float4 A = la4[h];
        float4 B = lb4[h];
        float ax = x.x + (x.x * (A.x * B.x)) * 0.5f;
        float ay = x.y + (x.y * (A.y * B.y)) * 0.5f;
        float az = x.z + (x.z * (A.z * B.z)) * 0.5f;
        float aw = x.w + (x.w * (A.w * B.w)) * 0.5f;
        ma = fmaxf(ma, fmaxf(fmaxf(fabsf(ax), fabsf(ay)),
                             fmaxf(fabsf(az), fabsf(aw))));
    }
#pragma unroll
    for (int m = 32; m; m >>= 1) ma = fmaxf(ma, __shfl_xor(ma, m));
    if (lane == 0) sm[wid] = ma;
    __syncthreads();
    if (t == 0)
        atomicMax(reinterpret_cast<unsigned*>(&scal[11]),
                  __float_as_uint(fmaxf(fmaxf(sm[0], sm[1]), fmaxf(sm[2], sm[3]))));
}

// flag==1 only: re-quant with adapted values (exact flag-1 branch). Early-exits otherwise.
__global__ __launch_bounds__(256) void fixup_quant_kernel(
    const float4* __restrict__ X4, const float4* __restrict__ la4,
    const float4* __restrict__ lb4, const float* __restrict__ scal,
    float4* __restrict__ out4) {
    if (!(scal[8] / (scal[9] + EPSV) > 0.35f)) return;
    const float mv = __uint_as_float(reinterpret_cast<const unsigned*>(scal)[11]);
    const float scale = (mv < EPSV) ? 1.0f : mv / 7.0f;
    const size_t total4 = (size_t)NR * HC / 4;
    for (size_t i = (size_t)blockIdx.x * blockDim.x + threadIdx.x; i < total4;
         i += (size_t)gridDim.x * blockDim.x) {
        float4 x = X4[i];
        int h = (int)(i & (H4 - 1));
        float4 A = la4[h];
        float4 B = lb4[h];
        x.x += (x.x * (A.x * B.x)) * 0.5f;
        x.y += (x.y * (A.y * B.y)) * 0.5f;
        x.z += (x.z * (A.z * B.z)) * 0.5f;
        x.w += (x.w * (A.w * B.w)) * 0.5f;
        float4 o;
        o.x = fminf(fmaxf(rintf(x.x / scale), -8.f), 7.f) * scale;
        o.y = fminf(fmaxf(rintf(x.y / scale), -8.f), 7.f) * scale;
        o.z = fminf(fmaxf(rintf(x.z / scale), -8.f), 7.f) * scale;
        o.w = fminf(fmaxf(rintf(x.w / scale), -8.f), 7.f) * scale;
        out4[i] = o;
    }
}

extern "C" void kernel_launch(void* const* d_in, const int* in_sizes, int n_in,
                              void* d_out, int out_size, void* d_ws, size_t ws_size,
                              hipStream_t stream) {
    const float4* X4 = reinterpret_cast<const float4*>(d_in[0]);
    const float4* la4 = reinterpret_cast<const float4*>(d_in[1]);
    const float4* lb4 = reinterpret_cast<const float4*>(d_in[2]);
    const float4* v04 = reinterpret_cast<const float4*>(d_in[3]);
    float* ws = (float*)d_ws;
    float* w1 = ws;
    float* w2 = ws + HC;
    float* scal = ws + 2 * HC;
    float4* part4 = reinterpret_cast<float4*>(d_out);
    float4* out4 = reinterpret_cast<float4*>(d_out);
    const float* part = (const float*)d_out;

    // zero w1 + w2 + scal in one memset
    hipMemsetAsync(ws, 0, (2 * HC + 16) * sizeof(float), stream);

    // power iteration 1 (+ frob, max|X| — scalars only)
    xtxv_kernel<0, 1><<<NB, 256, 0, stream>>>(X4, v04, part4, scal);
    reduce_part_kernel<<<NB, 256, 0, stream>>>(part, w1);

    // power iteration 2
    xtxv_kernel<1, 0><<<NB, 256, 0, stream>>>(X4, reinterpret_cast<const float4*>(w1),
                                              part4, scal);
    reduce_part_kernel<<<NB, 256, 0, stream>>>(part, w2);

    // sigma^2 + optimistic quant in one pass (overwrites partial scratch)
    quantsig_kernel<<<NB, 256, 0, stream>>>(X4, reinterpret_cast<const float4*>(w2),
                                            scal, out4);

    // rare flag==1 path: compute adapted max, then re-quant (both early-exit on flag==0)
    fixup_max_kernel<<<2048, 256, 0, stream>>>(X4, la4, lb4, scal);
    fixup_quant_kernel<<<2048, 256, 0, stream>>>(X4, la4, lb4, scal, out4);
}